// Round 12
// baseline (311.868 us; speedup 1.0000x reference)
//
#include <hip/hip_runtime.h>
#include <hip/hip_bf16.h>

// Problem constants
#define BB 2
#define SS 2048
#define DD 2048
#define HH 16
#define DKK 128
#define MM (BB*SS)   // 4096 token rows

typedef unsigned short u16;
typedef short bf16x8 __attribute__((ext_vector_type(8)));
typedef unsigned short u16x8 __attribute__((ext_vector_type(8)));
typedef float f32x4 __attribute__((ext_vector_type(4)));

static __device__ __forceinline__ f32x4 mfma_bf16(bf16x8 a, bf16x8 b, f32x4 c) {
  return __builtin_amdgcn_mfma_f32_16x16x32_bf16(a, b, c, 0, 0, 0);
}

// fp32 -> bf16 RNE (bit-twiddle, prepass)
static __device__ __forceinline__ u16 f2b(float f) {
  unsigned int u = __float_as_uint(f);
  u = (u + 0x7FFFu + ((u >> 16) & 1u)) >> 16;
  return (u16)u;
}

// fp32 -> bf16 RNE via v_cvt_pk_bf16_f32 (1 VALU op; hot path)
static __device__ __forceinline__ u16 f2bq(float f) {
  unsigned int r;
  asm("v_cvt_pk_bf16_f32 %0, %1, %2" : "=v"(r) : "v"(f), "v"(f));
  return (u16)r;
}

// async global->LDS, 16B/lane. LDS dest = wave-uniform base + lane*16.
static __device__ __forceinline__ void gl16(const u16* g, u16* l) {
  __builtin_amdgcn_global_load_lds(
      (const __attribute__((address_space(1))) unsigned int*)(const void*)g,
      (__attribute__((address_space(3))) unsigned int*)(void*)l, 16, 0, 0);
}

// Fused fp32->bf16 for all 7 tensors (8 elems/thread, 16B stores) PLUS the
// RoPE cos/sin table (last 64 blocks) — one launch instead of two.
struct F2BArgs { const float* src[7]; u16* dst[7]; const float* fa; float* cs; };
__global__ __launch_bounds__(256) void k_f2bf_all(F2BArgs a) {
  int bid = blockIdx.x;
  if (bid >= 20480) {
    const int t0 = ((bid - 20480) * 256 + threadIdx.x) * 8;
    float4 a0 = *reinterpret_cast<const float4*>(a.fa + t0);
    float4 a1 = *reinterpret_cast<const float4*>(a.fa + t0 + 4);
    float4 o0, o1, o2, o3;
    o0.x = cosf(a0.x); o0.y = sinf(a0.x); o0.z = cosf(a0.y); o0.w = sinf(a0.y);
    o1.x = cosf(a0.z); o1.y = sinf(a0.z); o1.z = cosf(a0.w); o1.w = sinf(a0.w);
    o2.x = cosf(a1.x); o2.y = sinf(a1.x); o2.z = cosf(a1.y); o2.w = sinf(a1.y);
    o3.x = cosf(a1.z); o3.y = sinf(a1.z); o3.z = cosf(a1.w); o3.w = sinf(a1.w);
    float* out = a.cs + 2 * t0;
    *reinterpret_cast<float4*>(out)      = o0;
    *reinterpret_cast<float4*>(out + 4)  = o1;
    *reinterpret_cast<float4*>(out + 8)  = o2;
    *reinterpret_cast<float4*>(out + 12) = o3;
    return;
  }
  int buf, local;
  if (bid < 12288) { buf = bid >> 12; local = bid & 4095; }
  else { int t = bid - 12288; buf = 3 + (t >> 11); local = t & 2047; }
  const int i = (local * 256 + threadIdx.x) * 8;
  const float* in = a.src[buf];
  float4 v0 = *reinterpret_cast<const float4*>(in + i);
  float4 v1 = *reinterpret_cast<const float4*>(in + i + 4);
  u16x8 o;
  o[0]=f2b(v0.x); o[1]=f2b(v0.y); o[2]=f2b(v0.z); o[3]=f2b(v0.w);
  o[4]=f2b(v1.x); o[5]=f2b(v1.y); o[6]=f2b(v1.z); o[7]=f2b(v1.w);
  *reinterpret_cast<u16x8*>(a.dst[buf] + i) = o;
}

struct GemmJob { const u16* A; const u16* W; const float* bias; void* out; int mode; };
struct GemmArgs { GemmJob job[3]; };

// ============================================================================
// k_gemm3: 128x128 tile, BK=64, LDS double-buffer, issue-next-tile-first
// (round-7 best-measured structure, frozen).
// ============================================================================
__global__ __launch_bounds__(256, 2) void k_gemm3(GemmArgs ga, const float* __restrict__ cs) {
  const GemmJob J = ga.job[blockIdx.z];
  const u16* __restrict__ A = J.A;
  const u16* __restrict__ W = J.W;
  const int mode = J.mode;
  const int K = DD, N = DD;
  const int KT = K / 64;   // 32

  __shared__ __align__(16) u16 sA[2][128 * 64];   // 32 KiB
  __shared__ __align__(16) u16 sB[2][128 * 64];   // 32 KiB
  const int tid = threadIdx.x;
  const int l  = tid & 63;
  const int w  = tid >> 6;
  const int wr = w >> 1, wc = w & 1;
  const int bm = blockIdx.x * 128, bn = blockIdx.y * 128;
  const int lr = l & 15;
  const int lg = l >> 4;

  f32x4 acc[4][4];
#pragma unroll
  for (int mi = 0; mi < 4; mi++)
#pragma unroll
    for (int ni = 0; ni < 4; ni++)
#pragma unroll
      for (int j = 0; j < 4; j++) acc[mi][ni][j] = 0.0f;

  const int srcx = ((l & 7) * 8) ^ ((l >> 3) * 8);
  const u16* gAl = A + (size_t)(bm + w*32 + (l >> 3)) * K + srcx;
  const u16* gBl = W + (size_t)(bn + w*32 + (l >> 3)) * K + srcx;

  const int rx = (lr & 7) * 8;

  auto stage = [&](int kt) {
    u16* dA = &sA[kt & 1][(w * 32) * 64];
    u16* dB = &sB[kt & 1][(w * 32) * 64];
    const int k0 = kt * 64;
#pragma unroll
    for (int i = 0; i < 4; i++) gl16(gAl + (size_t)i*8*K + k0, dA + i * 512);
#pragma unroll
    for (int i = 0; i < 4; i++) gl16(gBl + (size_t)i*8*K + k0, dB + i * 512);
  };

  stage(0);
  __syncthreads();

#pragma unroll 1
  for (int t = 0; t < KT; t++) {
    if (t + 1 < KT) stage(t + 1);
    const u16* a_ = sA[t & 1];
    const u16* b_ = sB[t & 1];
#pragma unroll
    for (int kk = 0; kk < 2; kk++) {
      bf16x8 af[4], bfv[4];
#pragma unroll
      for (int i = 0; i < 4; i++)
        af[i]  = *reinterpret_cast<const bf16x8*>(
            a_ + (wr*64 + i*16 + lr) * 64 + ((kk*32 + lg*8) ^ rx));
#pragma unroll
      for (int i = 0; i < 4; i++)
        bfv[i] = *reinterpret_cast<const bf16x8*>(
            b_ + (wc*64 + i*16 + lr) * 64 + ((kk*32 + lg*8) ^ rx));
#pragma unroll
      for (int mi = 0; mi < 4; mi++)
#pragma unroll
        for (int ni = 0; ni < 4; ni++)
          acc[mi][ni] = mfma_bf16(af[mi], bfv[ni], acc[mi][ni]);
    }
    __syncthreads();
  }

#pragma unroll
  for (int mi = 0; mi < 4; mi++) {
#pragma unroll
    for (int ni = 0; ni < 4; ni++) {
      const int col = bn + wc*64 + ni*16 + lr;
      const float bv = J.bias[col];
#pragma unroll
      for (int r = 0; r < 4; r++) {
        const int row = bm + wr*64 + mi*16 + lg*4 + r;
        float v = acc[mi][ni][r] + bv;
        if (mode & 1) {
          const int s  = row & (SS - 1);
          const int dk = col & (DKK - 1);
          const int p  = dk >> 1;
          const float2 csv = *reinterpret_cast<const float2*>(cs + (size_t)(s*64 + p)*2);
          const float other = __shfl_xor(v, 1);
          const float sgn = (dk & 1) ? csv.y : -csv.y;
          v = v * csv.x + other * sgn;
          if (mode == 3) v *= 0.12751744f;   // (1/sqrt(128)) * log2(e)
        }
        if (mode == 2) {
          reinterpret_cast<float*>(J.out)[(size_t)row * N + col] = v;
        } else {
          reinterpret_cast<u16*>(J.out)[(size_t)row * N + col] = f2b(v);
        }
      }
    }
  }
}

// ============================================================================
// Flash attention, causal, exp2 domain. 8-wave kv-split (see header comment
// in the round-12 analysis): 256 blocks = 8 pairs x 32 bh; per block two
// 4-wave groups split each 128-row tile's 64-key subtile stream even/odd
// (jj+1 subtiles each), 32 q-rows/wave (mt=2), group-private K-dbuf/VT/PL,
// in-LDS flash merge per tile. m floored at -30000. LDS 133 KB, 1 block/CU,
// 2 waves/SIMD, tiles paired (15-p, p) -> uniform 34 units/block, no tail.
// ============================================================================
__global__ __launch_bounds__(512, 2) void k_attn(const u16* __restrict__ Qp,
                                                 const u16* __restrict__ Kp,
                                                 const u16* __restrict__ Vp,
                                                 u16* __restrict__ Op) {
  const int bid = blockIdx.x;
  const int p  = bid >> 5;            // 0..7 (pair index)
  const int bh = bid & 31;
  const int h  = bh & 15;
  const int b  = bh >> 4;
  const int tid = threadIdx.x;        // 0..511
  const int l  = tid & 63;
  const int w  = tid >> 6;            // 0..7
  const int g  = w >> 2;              // group 0/1
  const int wg = w & 3;               // wave within group
  const int lr = l & 15, lg = l >> 4;

  __shared__ __align__(16) u16 Klds[2][2][64 * 128];  // 64 KB [group][dbuf]
  __shared__ __align__(16) u16 VT[2][128 * 64];       // 32 KB
  __shared__ __align__(16) u16 PL[2][4][32][72];      // 36 KB
  __shared__ float mlbuf[128][2];                     // 1 KB (m, l from group 1)

  int koff[4];
#pragma unroll
  for (int i = 0; i < 4; i++) {
    const int row = wg*16 + i*4 + (l >> 4);
    koff[i] = row * DD + (((l & 15) * 8) ^ ((row & 7) * 8));
  }
  const u16* kbase = Kp + (size_t)b * SS * DD + h * DKK;

  const int gtid = tid & 255;
  const int k0v = (gtid >> 5) * 8;   // 0,8,...,56
  const int d0  = (gtid & 31) * 4;   // 0,4,...,124
  const u16* vbase = Vp + (size_t)b * SS * DD + h * DKK + (size_t)k0v * DD + d0;

  uint2 vr[8];

  auto stageK = [&](int s, int bufq) {   // s = global 64-key subtile index
    const u16* kb = kbase + (size_t)s * (64 * DD);
    u16* dst = &Klds[g][bufq][(wg * 16) * 128];
#pragma unroll
    for (int i = 0; i < 4; i++) gl16(kb + koff[i], dst + i * 512);
  };
  auto prefV = [&](int s) {
    const u16* vb = vbase + (size_t)s * (64 * DD);
#pragma unroll
    for (int c = 0; c < 8; c++) vr[c] = *reinterpret_cast<const uint2*>(vb + c * DD);
  };

#pragma unroll 1
  for (int half = 0; half < 2; half++) {
    const int jj = half ? p : (15 - p);   // 128-row tile index
    const int q0 = jj * 128;

    bf16x8 qf[2][4];
#pragma unroll
    for (int mt = 0; mt < 2; mt++) {
      const size_t qrow = (size_t)(b*SS + q0 + wg*32 + mt*16 + lr) * DD + h*DKK;
#pragma unroll
      for (int kk = 0; kk < 4; kk++)
        qf[mt][kk] = *reinterpret_cast<const bf16x8*>(Qp + qrow + kk*32 + lg*8);
    }

    float m[2][4], lsum[2][4];
    f32x4 oacc[2][8];
#pragma unroll
    for (int mt = 0; mt < 2; mt++)
#pragma unroll
      for (int r = 0; r < 4; r++) { m[mt][r] = -30000.0f; lsum[mt][r] = 0.0f; }
#pragma unroll
    for (int mt = 0; mt < 2; mt++)
#pragma unroll
      for (int dt = 0; dt < 8; dt++)
#pragma unroll
        for (int jq = 0; jq < 4; jq++) oacc[mt][dt][jq] = 0.0f;

    int cur = 0;
    stageK(g, 0);    // group g's first subtile s = g
    prefV(g);

#pragma unroll 1
    for (int u = 0; u <= jj; u++) {
      __syncthreads();
#pragma unroll
      for (int dj = 0; dj < 4; dj++) {
        const int row = d0 + dj;
        const int col = k0v ^ (((row ^ (row >> 3)) & 7) * 8);
        u16x8 pk;
#pragma unroll
        for (int jq = 0; jq < 8; jq++) pk[jq] = reinterpret_cast<const u16*>(&vr[jq])[dj];
        *reinterpret_cast<u16x8*>(&VT[g][row * 64 + col]) = pk;
      }
      __syncthreads();

      const bool hasnext = (u < jj);
      if (hasnext) {
        prefV(2*(u+1) + g);
        stageK(2*(u+1) + g, cur ^ 1);
      }

      f32x4 sa[2][4];
#pragma unroll
      for (int mt = 0; mt < 2; mt++)
#pragma unroll
        for (int kt = 0; kt < 4; kt++)
#pragma unroll
          for (int jq = 0; jq < 4; jq++) sa[mt][kt][jq] = 0.0f;
      const u16* kl = &Klds[g][cur][0];
      __builtin_amdgcn_s_setprio(1);
#pragma unroll
      for (int kk = 0; kk < 4; kk++) {
#pragma unroll
        for (int kt = 0; kt < 4; kt++) {
          const int row = kt*16 + lr;
          const bf16x8 kf = *reinterpret_cast<const bf16x8*>(
              kl + row * 128 + ((kk*32 + lg*8) ^ ((row & 7) * 8)));
#pragma unroll
          for (int mt = 0; mt < 2; mt++)
            sa[mt][kt] = mfma_bf16(qf[mt][kk], kf, sa[mt][kt]);
        }
      }
      __builtin_amdgcn_s_setprio(0);

      if (u == jj) {
#pragma unroll
        for (int kt = 0; kt < 4; kt++) {
          const int key = g*64 + kt*16 + lr;           // tile-local key
#pragma unroll
          for (int mt = 0; mt < 2; mt++)
#pragma unroll
            for (int r = 0; r < 4; r++) {
              const int lrow = wg*32 + mt*16 + lg*4 + r;
              if (key > lrow) sa[mt][kt][r] = -1e9f;
            }
        }
      }

      float pm[2][4];
#pragma unroll
      for (int mt = 0; mt < 2; mt++)
#pragma unroll
        for (int r = 0; r < 4; r++)
          pm[mt][r] = fmaxf(fmaxf(sa[mt][0][r], sa[mt][1][r]),
                            fmaxf(sa[mt][2][r], sa[mt][3][r]));
      bool ok = true;
#pragma unroll
      for (int mt = 0; mt < 2; mt++)
#pragma unroll
        for (int r = 0; r < 4; r++) ok = ok && (pm[mt][r] <= m[mt][r] + 8.0f);
      if (!__all(ok)) {
#pragma unroll
        for (int mt = 0; mt < 2; mt++)
#pragma unroll
          for (int r = 0; r < 4; r++) {
            float t = pm[mt][r];
#pragma unroll
            for (int d = 1; d < 16; d <<= 1) t = fmaxf(t, __shfl_xor(t, d));
            const float mnew = fmaxf(m[mt][r], t);
            const float corr = exp2f(m[mt][r] - mnew);
            lsum[mt][r] *= corr;
#pragma unroll
            for (int dt = 0; dt < 8; dt++) oacc[mt][dt][r] *= corr;
            m[mt][r] = mnew;
          }
      }

#pragma unroll
      for (int mt = 0; mt < 2; mt++)
#pragma unroll
        for (int r = 0; r < 4; r++) {
          float rs = 0.0f;
#pragma unroll
          for (int kt = 0; kt < 4; kt++) {
            const float e = exp2f(sa[mt][kt][r] - m[mt][r]);
            rs += e;
            PL[g][wg][mt*16 + lg*4 + r][kt*16 + lr] = f2bq(e);
          }
          lsum[mt][r] += rs;
        }

      __builtin_amdgcn_s_setprio(1);
#pragma unroll
      for (int kk2 = 0; kk2 < 2; kk2++) {
        bf16x8 pa[2];
#pragma unroll
        for (int mt = 0; mt < 2; mt++)
          pa[mt] = *reinterpret_cast<const bf16x8*>(&PL[g][wg][mt*16 + lr][kk2*32 + lg*8]);
#pragma unroll
        for (int dt = 0; dt < 8; dt++) {
          const int row = dt*16 + lr;
          const bf16x8 vb = *reinterpret_cast<const bf16x8*>(
              &VT[g][row * 64 + ((kk2*32 + lg*8) ^ (((row ^ (row >> 3)) & 7) * 8))]);
#pragma unroll
          for (int mt = 0; mt < 2; mt++)
            oacc[mt][dt] = mfma_bf16(pa[mt], vb, oacc[mt][dt]);
        }
      }
      __builtin_amdgcn_s_setprio(0);

      if (hasnext) cur ^= 1;
    }

    float lred[2][4];
#pragma unroll
    for (int mt = 0; mt < 2; mt++)
#pragma unroll
      for (int r = 0; r < 4; r++) {
        float t = lsum[mt][r];
#pragma unroll
        for (int d = 1; d < 16; d <<= 1) t += __shfl_xor(t, d);
        lred[mt][r] = t;
      }

    __syncthreads();
    float* ob = (float*)&Klds[0][0][0];   // 128x128 f32 (reuses 64KB K region)
    if (g == 1) {
#pragma unroll
      for (int mt = 0; mt < 2; mt++)
#pragma unroll
        for (int r = 0; r < 4; r++) {
          const int lrow = wg*32 + mt*16 + lg*4 + r;
          if (lr == 0) { mlbuf[lrow][0] = m[mt][r]; mlbuf[lrow][1] = lred[mt][r]; }
#pragma unroll
          for (int dt = 0; dt < 8; dt++)
            ob[lrow * 128 + dt*16 + lr] = oacc[mt][dt][r];
        }
    }
    __syncthreads();
    if (g == 0) {
#pragma unroll
      for (int mt = 0; mt < 2; mt++)
#pragma unroll
        for (int r = 0; r < 4; r++) {
          const int lrow = wg*32 + mt*16 + lg*4 + r;
          const float m1 = mlbuf[lrow][0];
          const float l1 = mlbuf[lrow][1];
          const float ms = fmaxf(m[mt][r], m1);
          const float c0 = exp2f(m[mt][r] - ms);
          const float c1 = exp2f(m1 - ms);
          const float inv = 1.0f / (lred[mt][r] * c0 + l1 * c1);
          const size_t row = (size_t)(b*SS + q0 + lrow);
#pragma unroll
          for (int dt = 0; dt < 8; dt++) {
            const float o = (oacc[mt][dt][r] * c0 + ob[lrow * 128 + dt*16 + lr] * c1) * inv;
            Op[row * DD + h*DKK + dt*16 + lr] = f2bq(o);
          }
        }
    }
    __syncthreads();   // merge reads done before next half's staging overwrites
  }
}

extern "C" void kernel_launch(void* const* d_in, const int* in_sizes, int n_in,
                              void* d_out, int out_size, void* d_ws, size_t ws_size,
                              hipStream_t stream) {
  const float* q  = (const float*)d_in[0];
  const float* k  = (const float*)d_in[1];
  const float* v  = (const float*)d_in[2];
  const float* fa = (const float*)d_in[4];
  const float* wq = (const float*)d_in[5];
  const float* bq = (const float*)d_in[6];
  const float* wk = (const float*)d_in[7];
  const float* bk = (const float*)d_in[8];
  const float* wv = (const float*)d_in[9];
  const float* bv = (const float*)d_in[10];
  const float* wo = (const float*)d_in[11];
  const float* bo = (const float*)d_in[12];

  float* cs = (float*)d_ws;
  u16* bf = (u16*)((char*)d_ws + (size_t)262144 * sizeof(float));
  const size_t NX = (size_t)MM * DD;
  const size_t NW = (size_t)DD * DD;
  u16* q_bf  = bf;
  u16* k_bf  = q_bf + NX;
  u16* v_bf  = k_bf + NX;
  u16* wq_bf = v_bf + NX;
  u16* wk_bf = wq_bf + NW;
  u16* wv_bf = wk_bf + NW;
  u16* wo_bf = wv_bf + NW;
  u16* Qp    = wo_bf + NW;
  u16* Kp    = Qp + NX;
  u16* Vp    = Kp + NX;
  u16* Ao    = Vp + NX;

  F2BArgs fa7;
  fa7.src[0] = q;  fa7.dst[0] = q_bf;
  fa7.src[1] = k;  fa7.dst[1] = k_bf;
  fa7.src[2] = v;  fa7.dst[2] = v_bf;
  fa7.src[3] = wq; fa7.dst[3] = wq_bf;
  fa7.src[4] = wk; fa7.dst[4] = wk_bf;
  fa7.src[5] = wv; fa7.dst[5] = wv_bf;
  fa7.src[6] = wo; fa7.dst[6] = wo_bf;
  fa7.fa = fa;     fa7.cs = cs;
  k_f2bf_all<<<dim3(20544), 256, 0, stream>>>(fa7);

  GemmArgs gq;
  gq.job[0] = GemmJob{ q_bf, wq_bf, bq, (void*)Qp, 3 };
  gq.job[1] = GemmJob{ k_bf, wk_bf, bk, (void*)Kp, 1 };
  gq.job[2] = GemmJob{ v_bf, wv_bf, bv, (void*)Vp, 0 };
  k_gemm3<<<dim3(MM/128, DD/128, 3), 256, 0, stream>>>(gq, cs);

  // attention: 256 8-wave blocks, kv-split groups + paired 128-row tiles
  k_attn<<<dim3(256), 512, 0, stream>>>(Qp, Kp, Vp, Ao);

  GemmArgs go;
  go.job[0] = GemmJob{ Ao, wo_bf, bo, d_out, 2 };
  go.job[1] = go.job[0];
  go.job[2] = go.job[0];
  k_gemm3<<<dim3(MM/128, DD/128, 1), 256, 0, stream>>>(go, cs);
}

// Round 13
// 308.376 us; speedup vs baseline: 1.0113x; 1.0113x over previous
//
#include <hip/hip_runtime.h>
#include <hip/hip_bf16.h>

// Problem constants
#define BB 2
#define SS 2048
#define DD 2048
#define HH 16
#define DKK 128
#define MM (BB*SS)   // 4096 token rows

typedef unsigned short u16;
typedef short bf16x8 __attribute__((ext_vector_type(8)));
typedef unsigned short u16x8 __attribute__((ext_vector_type(8)));
typedef float f32x4 __attribute__((ext_vector_type(4)));

static __device__ __forceinline__ f32x4 mfma_bf16(bf16x8 a, bf16x8 b, f32x4 c) {
  return __builtin_amdgcn_mfma_f32_16x16x32_bf16(a, b, c, 0, 0, 0);
}

// fp32 -> bf16 RNE (bit-twiddle, prepass)
static __device__ __forceinline__ u16 f2b(float f) {
  unsigned int u = __float_as_uint(f);
  u = (u + 0x7FFFu + ((u >> 16) & 1u)) >> 16;
  return (u16)u;
}

// fp32 -> bf16 RNE via v_cvt_pk_bf16_f32 (1 VALU op; hot path)
static __device__ __forceinline__ u16 f2bq(float f) {
  unsigned int r;
  asm("v_cvt_pk_bf16_f32 %0, %1, %2" : "=v"(r) : "v"(f), "v"(f));
  return (u16)r;
}

// async global->LDS, 16B/lane. LDS dest = wave-uniform base + lane*16.
static __device__ __forceinline__ void gl16(const u16* g, u16* l) {
  __builtin_amdgcn_global_load_lds(
      (const __attribute__((address_space(1))) unsigned int*)(const void*)g,
      (__attribute__((address_space(3))) unsigned int*)(void*)l, 16, 0, 0);
}

// Fused fp32->bf16 for all 7 tensors (8 elems/thread, 16B stores) PLUS the
// RoPE cos/sin table (last 64 blocks) — one launch instead of two.
struct F2BArgs { const float* src[7]; u16* dst[7]; const float* fa; float* cs; };
__global__ __launch_bounds__(256) void k_f2bf_all(F2BArgs a) {
  int bid = blockIdx.x;
  if (bid >= 20480) {
    const int t0 = ((bid - 20480) * 256 + threadIdx.x) * 8;
    float4 a0 = *reinterpret_cast<const float4*>(a.fa + t0);
    float4 a1 = *reinterpret_cast<const float4*>(a.fa + t0 + 4);
    float4 o0, o1, o2, o3;
    o0.x = cosf(a0.x); o0.y = sinf(a0.x); o0.z = cosf(a0.y); o0.w = sinf(a0.y);
    o1.x = cosf(a0.z); o1.y = sinf(a0.z); o1.z = cosf(a0.w); o1.w = sinf(a0.w);
    o2.x = cosf(a1.x); o2.y = sinf(a1.x); o2.z = cosf(a1.y); o2.w = sinf(a1.y);
    o3.x = cosf(a1.z); o3.y = sinf(a1.z); o3.z = cosf(a1.w); o3.w = sinf(a1.w);
    float* out = a.cs + 2 * t0;
    *reinterpret_cast<float4*>(out)      = o0;
    *reinterpret_cast<float4*>(out + 4)  = o1;
    *reinterpret_cast<float4*>(out + 8)  = o2;
    *reinterpret_cast<float4*>(out + 12) = o3;
    return;
  }
  int buf, local;
  if (bid < 12288) { buf = bid >> 12; local = bid & 4095; }
  else { int t = bid - 12288; buf = 3 + (t >> 11); local = t & 2047; }
  const int i = (local * 256 + threadIdx.x) * 8;
  const float* in = a.src[buf];
  float4 v0 = *reinterpret_cast<const float4*>(in + i);
  float4 v1 = *reinterpret_cast<const float4*>(in + i + 4);
  u16x8 o;
  o[0]=f2b(v0.x); o[1]=f2b(v0.y); o[2]=f2b(v0.z); o[3]=f2b(v0.w);
  o[4]=f2b(v1.x); o[5]=f2b(v1.y); o[6]=f2b(v1.z); o[7]=f2b(v1.w);
  *reinterpret_cast<u16x8*>(a.dst[buf] + i) = o;
}

struct GemmJob { const u16* A; const u16* W; const float* bias; void* out; int mode; };
struct GemmArgs { GemmJob job[3]; };

// ============================================================================
// k_gemm3: 128x128 tile, BK=64, LDS double-buffer, issue-next-tile-first
// (round-7 best-measured structure, frozen).
// LDS 64 KiB -> 2 blocks/CU. mode: 0=bf16out,1=+RoPE,3=+RoPE+scale,2=fp32out.
// ============================================================================
__global__ __launch_bounds__(256, 2) void k_gemm3(GemmArgs ga, const float* __restrict__ cs) {
  const GemmJob J = ga.job[blockIdx.z];
  const u16* __restrict__ A = J.A;
  const u16* __restrict__ W = J.W;
  const int mode = J.mode;
  const int K = DD, N = DD;
  const int KT = K / 64;   // 32

  __shared__ __align__(16) u16 sA[2][128 * 64];   // 32 KiB
  __shared__ __align__(16) u16 sB[2][128 * 64];   // 32 KiB
  const int tid = threadIdx.x;
  const int l  = tid & 63;
  const int w  = tid >> 6;
  const int wr = w >> 1, wc = w & 1;
  const int bm = blockIdx.x * 128, bn = blockIdx.y * 128;
  const int lr = l & 15;
  const int lg = l >> 4;

  f32x4 acc[4][4];
#pragma unroll
  for (int mi = 0; mi < 4; mi++)
#pragma unroll
    for (int ni = 0; ni < 4; ni++)
#pragma unroll
      for (int j = 0; j < 4; j++) acc[mi][ni][j] = 0.0f;

  const int srcx = ((l & 7) * 8) ^ ((l >> 3) * 8);
  const u16* gAl = A + (size_t)(bm + w*32 + (l >> 3)) * K + srcx;
  const u16* gBl = W + (size_t)(bn + w*32 + (l >> 3)) * K + srcx;

  const int rx = (lr & 7) * 8;

  auto stage = [&](int kt) {
    u16* dA = &sA[kt & 1][(w * 32) * 64];
    u16* dB = &sB[kt & 1][(w * 32) * 64];
    const int k0 = kt * 64;
#pragma unroll
    for (int i = 0; i < 4; i++) gl16(gAl + (size_t)i*8*K + k0, dA + i * 512);
#pragma unroll
    for (int i = 0; i < 4; i++) gl16(gBl + (size_t)i*8*K + k0, dB + i * 512);
  };

  stage(0);
  __syncthreads();   // drains tile-0 loads

#pragma unroll 1
  for (int t = 0; t < KT; t++) {
    if (t + 1 < KT) stage(t + 1);          // issue FIRST: flies under compute
    const u16* a_ = sA[t & 1];
    const u16* b_ = sB[t & 1];
#pragma unroll
    for (int kk = 0; kk < 2; kk++) {
      bf16x8 af[4], bfv[4];
#pragma unroll
      for (int i = 0; i < 4; i++)
        af[i]  = *reinterpret_cast<const bf16x8*>(
            a_ + (wr*64 + i*16 + lr) * 64 + ((kk*32 + lg*8) ^ rx));
#pragma unroll
      for (int i = 0; i < 4; i++)
        bfv[i] = *reinterpret_cast<const bf16x8*>(
            b_ + (wc*64 + i*16 + lr) * 64 + ((kk*32 + lg*8) ^ rx));
#pragma unroll
      for (int mi = 0; mi < 4; mi++)
#pragma unroll
        for (int ni = 0; ni < 4; ni++)
          acc[mi][ni] = mfma_bf16(af[mi], bfv[ni], acc[mi][ni]);
    }
    __syncthreads();   // drains t+1 loads (issued ~compute ago) + LDS hazards
  }

  // Epilogue. D-layout: col = lane&15, row = (lane>>4)*4 + reg.
#pragma unroll
  for (int mi = 0; mi < 4; mi++) {
#pragma unroll
    for (int ni = 0; ni < 4; ni++) {
      const int col = bn + wc*64 + ni*16 + lr;
      const float bv = J.bias[col];
#pragma unroll
      for (int r = 0; r < 4; r++) {
        const int row = bm + wr*64 + mi*16 + lg*4 + r;
        float v = acc[mi][ni][r] + bv;
        if (mode & 1) {
          const int s  = row & (SS - 1);
          const int dk = col & (DKK - 1);
          const int p  = dk >> 1;
          const float2 csv = *reinterpret_cast<const float2*>(cs + (size_t)(s*64 + p)*2);
          const float other = __shfl_xor(v, 1);
          const float sgn = (dk & 1) ? csv.y : -csv.y;
          v = v * csv.x + other * sgn;
          if (mode == 3) v *= 0.12751744f;   // (1/sqrt(128)) * log2(e)
        }
        if (mode == 2) {
          reinterpret_cast<float*>(J.out)[(size_t)row * N + col] = v;
        } else {
          reinterpret_cast<u16*>(J.out)[(size_t)row * N + col] = f2b(v);
        }
      }
    }
  }
}

// ============================================================================
// Flash attention, causal, exp2 domain. 64-row q-tiles, KVBLK=64, PAIRED:
// block (p, bh) processes tiles j_hi = 31-p then j_lo = p sequentially ->
// cost = (32-p) + (p+1) = 33 kv-units for EVERY block. 512 blocks, all
// resident (2/CU), zero tail by construction. (r12's 8-wave kv-split with
// in-LDS merge measured -13 µs WORSE: 1 block/CU loses cross-block overlap
// at the per-subtile barrier rendezvous, and the merge adds barriers.)
// 4 waves x 16 q-rows; kv = 0..j, diagonal mask only at kv == j.
// LDS 57 KB (K dbuf 32 + VT 16 + PL 9) -> 2 blocks/CU.
// ============================================================================
__global__ __launch_bounds__(256, 2) void k_attn(const u16* __restrict__ Qp,
                                                 const u16* __restrict__ Kp,
                                                 const u16* __restrict__ Vp,
                                                 u16* __restrict__ Op) {
  const int bid = blockIdx.x;
  const int p  = bid >> 5;            // 0..15 (pair index)
  const int bh = bid & 31;
  const int h  = bh & 15;
  const int b  = bh >> 4;
  const int tid = threadIdx.x;
  const int l  = tid & 63, w = tid >> 6;
  const int lr = l & 15, lg = l >> 4;

  __shared__ __align__(16) u16 Klds[2 * 64 * 128];  // 32 KB (dbuf)
  __shared__ __align__(16) u16 VT[128 * 64];        // 16 KB
  __shared__ __align__(16) u16 PL[4][16][72];       // 9 KB

  // K staging: wave w stages rows [w*16, w*16+16), 4 gl16 of 4 rows each.
  int koff[4];
#pragma unroll
  for (int i = 0; i < 4; i++) {
    const int row = w*16 + i*4 + (l >> 4);
    koff[i] = row * DD + (((l & 15) * 8) ^ ((row & 7) * 8));
  }
  const u16* kbase = Kp + (size_t)b * SS * DD + h * DKK;

  // V staging: thread -> keys k0v..k0v+7 (8 rows) x d-range d0..d0+3 (uint2).
  const int k0v = (tid >> 5) * 8;   // 0,8,...,56
  const int d0  = (tid & 31) * 4;   // 0,4,...,124
  const u16* vbase = Vp + (size_t)b * SS * DD + h * DKK + (size_t)k0v * DD + d0;

  uint2 vr[8];

  auto stageK = [&](int nk, int bufq) {
    const u16* kb = kbase + (size_t)nk * (64 * DD);
    u16* dst = Klds + bufq * 8192 + (w * 16) * 128;
#pragma unroll
    for (int i = 0; i < 4; i++) gl16(kb + koff[i], dst + i * 512);
  };
  auto prefV = [&](int nk) {
    const u16* vb = vbase + (size_t)nk * (64 * DD);
#pragma unroll
    for (int c = 0; c < 8; c++) vr[c] = *reinterpret_cast<const uint2*>(vb + c * DD);
  };

#pragma unroll 1
  for (int half = 0; half < 2; half++) {
    const int j  = half ? p : (31 - p);   // tile pair: 31-p then p
    const int q0 = j * 64;

    if (half) __syncthreads();   // half-0's final Klds/VT reads done before restage

    int cur = 0;
    stageK(0, 0);
    prefV(0);

    // Hoist Q fragments: 16 rows/wave x 4 k-slices
    bf16x8 qf[4];
    {
      const size_t qrow = (size_t)(b*SS + q0 + w*16 + lr) * DD + h*DKK;
#pragma unroll
      for (int kk = 0; kk < 4; kk++)
        qf[kk] = *reinterpret_cast<const bf16x8*>(Qp + qrow + kk*32 + lg*8);
    }

    float m[4], lsum[4];
    f32x4 oacc[8];
#pragma unroll
    for (int r = 0; r < 4; r++) { m[r] = -INFINITY; lsum[r] = 0.0f; }
#pragma unroll
    for (int dt = 0; dt < 8; dt++)
#pragma unroll
      for (int jj = 0; jj < 4; jj++) oacc[dt][jj] = 0.0f;

#pragma unroll 1
    for (int kv = 0; kv <= j; kv++) {
      __syncthreads();   // prev iter LDS reads done; K[cur] gl16 + vr loads drained
      // write prefetched V -> swizzled VT: VT[row=d][col=key ^ g(row)]
#pragma unroll
      for (int dj = 0; dj < 4; dj++) {
        const int row = d0 + dj;
        const int col = k0v ^ (((row ^ (row >> 3)) & 7) * 8);
        u16x8 pk;
#pragma unroll
        for (int jq = 0; jq < 8; jq++) pk[jq] = reinterpret_cast<const u16*>(&vr[jq])[dj];
        *reinterpret_cast<u16x8*>(VT + row * 64 + col) = pk;
      }
      __syncthreads();   // VT ready; K[cur] visible to all waves

      const bool hasnext = (kv < j);
      if (hasnext) {
        prefV(kv + 1);               // global->reg, hides under compute
        stageK(kv + 1, cur ^ 1);     // gl16, drained at next top barrier
      }

      // ---- S = Q K^T (16 q-rows x 64 keys per wave) ----
      f32x4 sa[4];
#pragma unroll
      for (int kt = 0; kt < 4; kt++)
#pragma unroll
        for (int jj = 0; jj < 4; jj++) sa[kt][jj] = 0.0f;
      const u16* kl = Klds + cur * 8192;
      __builtin_amdgcn_s_setprio(1);
#pragma unroll
      for (int kk = 0; kk < 4; kk++) {
#pragma unroll
        for (int kt = 0; kt < 4; kt++) {
          const int row = kt*16 + lr;
          const bf16x8 kf = *reinterpret_cast<const bf16x8*>(
              kl + row * 128 + ((kk*32 + lg*8) ^ ((row & 7) * 8)));
          sa[kt] = mfma_bf16(qf[kk], kf, sa[kt]);
        }
      }
      __builtin_amdgcn_s_setprio(0);

      // causal mask: only the diagonal tile (kv == j) straddles
      if (kv == j) {
#pragma unroll
        for (int kt = 0; kt < 4; kt++) {
          const int key = kt*16 + lr;                  // within tile
#pragma unroll
          for (int r = 0; r < 4; r++) {
            const int qv = w*16 + lg*4 + r;            // within tile
            if (key > qv) sa[kt][r] = -1e9f;
          }
        }
      }

      // defer-max (THR=8): lane-local check, rescale rarely
      float pm[4];
#pragma unroll
      for (int r = 0; r < 4; r++)
        pm[r] = fmaxf(fmaxf(sa[0][r], sa[1][r]), fmaxf(sa[2][r], sa[3][r]));
      bool ok = true;
#pragma unroll
      for (int r = 0; r < 4; r++) ok = ok && (pm[r] <= m[r] + 8.0f);
      if (!__all(ok)) {
#pragma unroll
        for (int r = 0; r < 4; r++) {
          float t = pm[r];
#pragma unroll
          for (int d = 1; d < 16; d <<= 1) t = fmaxf(t, __shfl_xor(t, d));
          const float mnew = fmaxf(m[r], t);
          const float corr = exp2f(m[r] - mnew);
          lsum[r] *= corr;
#pragma unroll
          for (int dt = 0; dt < 8; dt++) oacc[dt][r] *= corr;
          m[r] = mnew;
        }
      }

      // exp2 + lane-partial sums + P -> per-wave LDS
#pragma unroll
      for (int r = 0; r < 4; r++) {
        float rs = 0.0f;
#pragma unroll
        for (int kt = 0; kt < 4; kt++) {
          const float e = exp2f(sa[kt][r] - m[r]);
          rs += e;
          PL[w][lg*4 + r][kt*16 + lr] = f2bq(e);
        }
        lsum[r] += rs;
      }

      // ---- O += P V ----
      __builtin_amdgcn_s_setprio(1);
#pragma unroll
      for (int kk2 = 0; kk2 < 2; kk2++) {
        const bf16x8 pa = *reinterpret_cast<const bf16x8*>(&PL[w][lr][kk2*32 + lg*8]);
#pragma unroll
        for (int dt = 0; dt < 8; dt++) {
          const int row = dt*16 + lr;
          const bf16x8 vb = *reinterpret_cast<const bf16x8*>(
              VT + row * 64 + ((kk2*32 + lg*8) ^ (((row ^ (row >> 3)) & 7) * 8)));
          oacc[dt] = mfma_bf16(pa, vb, oacc[dt]);
        }
      }
      __builtin_amdgcn_s_setprio(0);

      if (hasnext) cur ^= 1;
    }

    // epilogue: reduce lane-partial lsum across 16 lanes, normalize, store
    float inv[4];
#pragma unroll
    for (int r = 0; r < 4; r++) {
      float t = lsum[r];
#pragma unroll
      for (int d = 1; d < 16; d <<= 1) t += __shfl_xor(t, d);
      inv[r] = 1.0f / t;
    }
#pragma unroll
    for (int dt = 0; dt < 8; dt++)
#pragma unroll
      for (int r = 0; r < 4; r++) {
        const size_t row = (size_t)(b*SS + q0 + w*16 + lg*4 + r);
        Op[row * DD + h*DKK + dt*16 + lr] = f2bq(oacc[dt][r] * inv[r]);
      }
  }
}

extern "C" void kernel_launch(void* const* d_in, const int* in_sizes, int n_in,
                              void* d_out, int out_size, void* d_ws, size_t ws_size,
                              hipStream_t stream) {
  const float* q  = (const float*)d_in[0];
  const float* k  = (const float*)d_in[1];
  const float* v  = (const float*)d_in[2];
  const float* fa = (const float*)d_in[4];
  const float* wq = (const float*)d_in[5];
  const float* bq = (const float*)d_in[6];
  const float* wk = (const float*)d_in[7];
  const float* bk = (const float*)d_in[8];
  const float* wv = (const float*)d_in[9];
  const float* bv = (const float*)d_in[10];
  const float* wo = (const float*)d_in[11];
  const float* bo = (const float*)d_in[12];

  float* cs = (float*)d_ws;
  u16* bf = (u16*)((char*)d_ws + (size_t)262144 * sizeof(float));
  const size_t NX = (size_t)MM * DD;
  const size_t NW = (size_t)DD * DD;
  u16* q_bf  = bf;
  u16* k_bf  = q_bf + NX;
  u16* v_bf  = k_bf + NX;
  u16* wq_bf = v_bf + NX;
  u16* wk_bf = wq_bf + NW;
  u16* wv_bf = wk_bf + NW;
  u16* wo_bf = wv_bf + NW;
  u16* Qp    = wo_bf + NW;
  u16* Kp    = Qp + NX;
  u16* Vp    = Kp + NX;
  u16* Ao    = Vp + NX;

  F2BArgs fa7;
  fa7.src[0] = q;  fa7.dst[0] = q_bf;
  fa7.src[1] = k;  fa7.dst[1] = k_bf;
  fa7.src[2] = v;  fa7.dst[2] = v_bf;
  fa7.src[3] = wq; fa7.dst[3] = wq_bf;
  fa7.src[4] = wk; fa7.dst[4] = wk_bf;
  fa7.src[5] = wv; fa7.dst[5] = wv_bf;
  fa7.src[6] = wo; fa7.dst[6] = wo_bf;
  fa7.fa = fa;     fa7.cs = cs;
  // 20480 conversion blocks + 64 cos/sin-table blocks
  k_f2bf_all<<<dim3(20544), 256, 0, stream>>>(fa7);

  // fused QKV projections: dbuf 128^2 kernel, grid 32x16x3 = 1536 blocks
  GemmArgs gq;
  gq.job[0] = GemmJob{ q_bf, wq_bf, bq, (void*)Qp, 3 };
  gq.job[1] = GemmJob{ k_bf, wk_bf, bk, (void*)Kp, 1 };
  gq.job[2] = GemmJob{ v_bf, wv_bf, bv, (void*)Vp, 0 };
  k_gemm3<<<dim3(MM/128, DD/128, 3), 256, 0, stream>>>(gq, cs);

  // attention: 512 paired blocks (cost-33 uniform), all resident, no tail
  k_attn<<<dim3(512), 256, 0, stream>>>(Qp, Kp, Vp, Ao);

  // output projection: 512 blocks = exactly 2 blocks/CU, one round
  GemmArgs go;
  go.job[0] = GemmJob{ Ao, wo_bf, bo, d_out, 2 };
  go.job[1] = go.job[0];
  go.job[2] = go.job[0];
  k_gemm3<<<dim3(MM/128, DD/128, 1), 256, 0, stream>>>(go, cs);
}

// Round 14
// 300.380 us; speedup vs baseline: 1.0382x; 1.0266x over previous
//
#include <hip/hip_runtime.h>
#include <hip/hip_bf16.h>

// Problem constants
#define BB 2
#define SS 2048
#define DD 2048
#define HH 16
#define DKK 128
#define MM (BB*SS)   // 4096 token rows

typedef unsigned short u16;
typedef short bf16x8 __attribute__((ext_vector_type(8)));
typedef unsigned short u16x8 __attribute__((ext_vector_type(8)));
typedef float f32x4 __attribute__((ext_vector_type(4)));

static __device__ __forceinline__ f32x4 mfma_bf16(bf16x8 a, bf16x8 b, f32x4 c) {
  return __builtin_amdgcn_mfma_f32_16x16x32_bf16(a, b, c, 0, 0, 0);
}

// fp32 -> bf16 RNE (bit-twiddle, prepass)
static __device__ __forceinline__ u16 f2b(float f) {
  unsigned int u = __float_as_uint(f);
  u = (u + 0x7FFFu + ((u >> 16) & 1u)) >> 16;
  return (u16)u;
}

// fp32 -> bf16 RNE via v_cvt_pk_bf16_f32 (1 VALU op; hot path)
static __device__ __forceinline__ u16 f2bq(float f) {
  unsigned int r;
  asm("v_cvt_pk_bf16_f32 %0, %1, %2" : "=v"(r) : "v"(f), "v"(f));
  return (u16)r;
}

// async global->LDS, 16B/lane. LDS dest = wave-uniform base + lane*16.
static __device__ __forceinline__ void gl16(const u16* g, u16* l) {
  __builtin_amdgcn_global_load_lds(
      (const __attribute__((address_space(1))) unsigned int*)(const void*)g,
      (__attribute__((address_space(3))) unsigned int*)(void*)l, 16, 0, 0);
}

// Fused fp32->bf16 for all 7 tensors (8 elems/thread, 16B stores) PLUS the
// RoPE cos/sin table (last 64 blocks) — one launch instead of two.
struct F2BArgs { const float* src[7]; u16* dst[7]; const float* fa; float* cs; };
__global__ __launch_bounds__(256) void k_f2bf_all(F2BArgs a) {
  int bid = blockIdx.x;
  if (bid >= 20480) {
    const int t0 = ((bid - 20480) * 256 + threadIdx.x) * 8;
    float4 a0 = *reinterpret_cast<const float4*>(a.fa + t0);
    float4 a1 = *reinterpret_cast<const float4*>(a.fa + t0 + 4);
    float4 o0, o1, o2, o3;
    o0.x = cosf(a0.x); o0.y = sinf(a0.x); o0.z = cosf(a0.y); o0.w = sinf(a0.y);
    o1.x = cosf(a0.z); o1.y = sinf(a0.z); o1.z = cosf(a0.w); o1.w = sinf(a0.w);
    o2.x = cosf(a1.x); o2.y = sinf(a1.x); o2.z = cosf(a1.y); o2.w = sinf(a1.y);
    o3.x = cosf(a1.z); o3.y = sinf(a1.z); o3.z = cosf(a1.w); o3.w = sinf(a1.w);
    float* out = a.cs + 2 * t0;
    *reinterpret_cast<float4*>(out)      = o0;
    *reinterpret_cast<float4*>(out + 4)  = o1;
    *reinterpret_cast<float4*>(out + 8)  = o2;
    *reinterpret_cast<float4*>(out + 12) = o3;
    return;
  }
  int buf, local;
  if (bid < 12288) { buf = bid >> 12; local = bid & 4095; }
  else { int t = bid - 12288; buf = 3 + (t >> 11); local = t & 2047; }
  const int i = (local * 256 + threadIdx.x) * 8;
  const float* in = a.src[buf];
  float4 v0 = *reinterpret_cast<const float4*>(in + i);
  float4 v1 = *reinterpret_cast<const float4*>(in + i + 4);
  u16x8 o;
  o[0]=f2b(v0.x); o[1]=f2b(v0.y); o[2]=f2b(v0.z); o[3]=f2b(v0.w);
  o[4]=f2b(v1.x); o[5]=f2b(v1.y); o[6]=f2b(v1.z); o[7]=f2b(v1.w);
  *reinterpret_cast<u16x8*>(a.dst[buf] + i) = o;
}

struct GemmJob { const u16* A; const u16* W; const float* bias; void* out; int mode; };
struct GemmArgs { GemmJob job[3]; };

// ============================================================================
// k_gemm3: 128x128 tile, BK=64, LDS double-buffer, issue-next-tile-first
// (round-7 best-measured structure) + T1 XCD-AWARE TILE SWIZZLE:
// HW round-robins consecutive workgroup ids across the 8 XCDs; remap so ids
// congruent mod 8 (= same XCD) form a contiguous chunk laid out as an 8x8
// bm x bn subgrid. Each XCD's ~64 resident blocks then share 8 A-panels +
// 8 W-panels (vs 4+16 under default dispatch) and each K-step strip is
// HBM-read once, L2-served 8x -> fewer ~900cy misses on the barrier-synced
// critical path. Bijective: 512 tiles = 8 chunks x 64 (both GEMM grids are
// 32x16). Mechanism check: FETCH_SIZE should drop 124 -> ~100 MiB.
// LDS 64 KiB -> 2 blocks/CU. mode: 0=bf16out,1=+RoPE,3=+RoPE+scale,2=fp32out.
// ============================================================================
__global__ __launch_bounds__(256, 2) void k_gemm3(GemmArgs ga, const float* __restrict__ cs) {
  const GemmJob J = ga.job[blockIdx.z];
  const u16* __restrict__ A = J.A;
  const u16* __restrict__ W = J.W;
  const int mode = J.mode;
  const int K = DD, N = DD;
  const int KT = K / 64;   // 32

  __shared__ __align__(16) u16 sA[2][128 * 64];   // 32 KiB
  __shared__ __align__(16) u16 sB[2][128 * 64];   // 32 KiB
  const int tid = threadIdx.x;
  const int l  = tid & 63;
  const int w  = tid >> 6;
  const int wr = w >> 1, wc = w & 1;

  // XCD swizzle: orig -> swz (same-XCD ids contiguous) -> 8x8 subgrid/chunk
  const int orig = blockIdx.y * 32 + blockIdx.x;      // 0..511
  const int swz  = (orig & 7) * 64 + (orig >> 3);     // bijective (512 % 8 == 0)
  const int ch   = swz >> 6;                          // chunk 0..7 (one per XCD)
  const int ti   = swz & 63;                          // pos in 8x8 subgrid
  const int bm = ((ch & 3) * 8 + (ti & 7)) * 128;     // 4 chunks along bm (32)
  const int bn = ((ch >> 2) * 8 + (ti >> 3)) * 128;   // 2 chunks along bn (16)

  const int lr = l & 15;
  const int lg = l >> 4;

  f32x4 acc[4][4];
#pragma unroll
  for (int mi = 0; mi < 4; mi++)
#pragma unroll
    for (int ni = 0; ni < 4; ni++)
#pragma unroll
      for (int j = 0; j < 4; j++) acc[mi][ni][j] = 0.0f;

  const int srcx = ((l & 7) * 8) ^ ((l >> 3) * 8);
  const u16* gAl = A + (size_t)(bm + w*32 + (l >> 3)) * K + srcx;
  const u16* gBl = W + (size_t)(bn + w*32 + (l >> 3)) * K + srcx;

  const int rx = (lr & 7) * 8;

  auto stage = [&](int kt) {
    u16* dA = &sA[kt & 1][(w * 32) * 64];
    u16* dB = &sB[kt & 1][(w * 32) * 64];
    const int k0 = kt * 64;
#pragma unroll
    for (int i = 0; i < 4; i++) gl16(gAl + (size_t)i*8*K + k0, dA + i * 512);
#pragma unroll
    for (int i = 0; i < 4; i++) gl16(gBl + (size_t)i*8*K + k0, dB + i * 512);
  };

  stage(0);
  __syncthreads();   // drains tile-0 loads

#pragma unroll 1
  for (int t = 0; t < KT; t++) {
    if (t + 1 < KT) stage(t + 1);          // issue FIRST: flies under compute
    const u16* a_ = sA[t & 1];
    const u16* b_ = sB[t & 1];
#pragma unroll
    for (int kk = 0; kk < 2; kk++) {
      bf16x8 af[4], bfv[4];
#pragma unroll
      for (int i = 0; i < 4; i++)
        af[i]  = *reinterpret_cast<const bf16x8*>(
            a_ + (wr*64 + i*16 + lr) * 64 + ((kk*32 + lg*8) ^ rx));
#pragma unroll
      for (int i = 0; i < 4; i++)
        bfv[i] = *reinterpret_cast<const bf16x8*>(
            b_ + (wc*64 + i*16 + lr) * 64 + ((kk*32 + lg*8) ^ rx));
#pragma unroll
      for (int mi = 0; mi < 4; mi++)
#pragma unroll
        for (int ni = 0; ni < 4; ni++)
          acc[mi][ni] = mfma_bf16(af[mi], bfv[ni], acc[mi][ni]);
    }
    __syncthreads();   // drains t+1 loads (issued ~compute ago) + LDS hazards
  }

  // Epilogue. D-layout: col = lane&15, row = (lane>>4)*4 + reg.
#pragma unroll
  for (int mi = 0; mi < 4; mi++) {
#pragma unroll
    for (int ni = 0; ni < 4; ni++) {
      const int col = bn + wc*64 + ni*16 + lr;
      const float bv = J.bias[col];
#pragma unroll
      for (int r = 0; r < 4; r++) {
        const int row = bm + wr*64 + mi*16 + lg*4 + r;
        float v = acc[mi][ni][r] + bv;
        if (mode & 1) {
          const int s  = row & (SS - 1);
          const int dk = col & (DKK - 1);
          const int p  = dk >> 1;
          const float2 csv = *reinterpret_cast<const float2*>(cs + (size_t)(s*64 + p)*2);
          const float other = __shfl_xor(v, 1);
          const float sgn = (dk & 1) ? csv.y : -csv.y;
          v = v * csv.x + other * sgn;
          if (mode == 3) v *= 0.12751744f;   // (1/sqrt(128)) * log2(e)
        }
        if (mode == 2) {
          reinterpret_cast<float*>(J.out)[(size_t)row * N + col] = v;
        } else {
          reinterpret_cast<u16*>(J.out)[(size_t)row * N + col] = f2b(v);
        }
      }
    }
  }
}

// ============================================================================
// Flash attention, causal, exp2 domain. 64-row q-tiles, KVBLK=64, PAIRED:
// block (p, bh) processes tiles j_hi = 31-p then j_lo = p sequentially ->
// cost = (32-p) + (p+1) = 33 kv-units for EVERY block. 512 blocks, all
// resident (2/CU), zero tail by construction (r11 best-measured; r12's
// 8-wave kv-split measured -13 µs: 1 block/CU loses cross-block overlap).
// 4 waves x 16 q-rows; kv = 0..j, diagonal mask only at kv == j.
// LDS 57 KB (K dbuf 32 + VT 16 + PL 9) -> 2 blocks/CU.
// ============================================================================
__global__ __launch_bounds__(256, 2) void k_attn(const u16* __restrict__ Qp,
                                                 const u16* __restrict__ Kp,
                                                 const u16* __restrict__ Vp,
                                                 u16* __restrict__ Op) {
  const int bid = blockIdx.x;
  const int p  = bid >> 5;            // 0..15 (pair index)
  const int bh = bid & 31;
  const int h  = bh & 15;
  const int b  = bh >> 4;
  const int tid = threadIdx.x;
  const int l  = tid & 63, w = tid >> 6;
  const int lr = l & 15, lg = l >> 4;

  __shared__ __align__(16) u16 Klds[2 * 64 * 128];  // 32 KB (dbuf)
  __shared__ __align__(16) u16 VT[128 * 64];        // 16 KB
  __shared__ __align__(16) u16 PL[4][16][72];       // 9 KB

  // K staging: wave w stages rows [w*16, w*16+16), 4 gl16 of 4 rows each.
  int koff[4];
#pragma unroll
  for (int i = 0; i < 4; i++) {
    const int row = w*16 + i*4 + (l >> 4);
    koff[i] = row * DD + (((l & 15) * 8) ^ ((row & 7) * 8));
  }
  const u16* kbase = Kp + (size_t)b * SS * DD + h * DKK;

  // V staging: thread -> keys k0v..k0v+7 (8 rows) x d-range d0..d0+3 (uint2).
  const int k0v = (tid >> 5) * 8;   // 0,8,...,56
  const int d0  = (tid & 31) * 4;   // 0,4,...,124
  const u16* vbase = Vp + (size_t)b * SS * DD + h * DKK + (size_t)k0v * DD + d0;

  uint2 vr[8];

  auto stageK = [&](int nk, int bufq) {
    const u16* kb = kbase + (size_t)nk * (64 * DD);
    u16* dst = Klds + bufq * 8192 + (w * 16) * 128;
#pragma unroll
    for (int i = 0; i < 4; i++) gl16(kb + koff[i], dst + i * 512);
  };
  auto prefV = [&](int nk) {
    const u16* vb = vbase + (size_t)nk * (64 * DD);
#pragma unroll
    for (int c = 0; c < 8; c++) vr[c] = *reinterpret_cast<const uint2*>(vb + c * DD);
  };

#pragma unroll 1
  for (int half = 0; half < 2; half++) {
    const int j  = half ? p : (31 - p);   // tile pair: 31-p then p
    const int q0 = j * 64;

    if (half) __syncthreads();   // half-0's final Klds/VT reads done before restage

    int cur = 0;
    stageK(0, 0);
    prefV(0);

    // Hoist Q fragments: 16 rows/wave x 4 k-slices
    bf16x8 qf[4];
    {
      const size_t qrow = (size_t)(b*SS + q0 + w*16 + lr) * DD + h*DKK;
#pragma unroll
      for (int kk = 0; kk < 4; kk++)
        qf[kk] = *reinterpret_cast<const bf16x8*>(Qp + qrow + kk*32 + lg*8);
    }

    float m[4], lsum[4];
    f32x4 oacc[8];
#pragma unroll
    for (int r = 0; r < 4; r++) { m[r] = -INFINITY; lsum[r] = 0.0f; }
#pragma unroll
    for (int dt = 0; dt < 8; dt++)
#pragma unroll
      for (int jj = 0; jj < 4; jj++) oacc[dt][jj] = 0.0f;

#pragma unroll 1
    for (int kv = 0; kv <= j; kv++) {
      __syncthreads();   // prev iter LDS reads done; K[cur] gl16 + vr loads drained
      // write prefetched V -> swizzled VT: VT[row=d][col=key ^ g(row)]
#pragma unroll
      for (int dj = 0; dj < 4; dj++) {
        const int row = d0 + dj;
        const int col = k0v ^ (((row ^ (row >> 3)) & 7) * 8);
        u16x8 pk;
#pragma unroll
        for (int jq = 0; jq < 8; jq++) pk[jq] = reinterpret_cast<const u16*>(&vr[jq])[dj];
        *reinterpret_cast<u16x8*>(VT + row * 64 + col) = pk;
      }
      __syncthreads();   // VT ready; K[cur] visible to all waves

      const bool hasnext = (kv < j);
      if (hasnext) {
        prefV(kv + 1);               // global->reg, hides under compute
        stageK(kv + 1, cur ^ 1);     // gl16, drained at next top barrier
      }

      // ---- S = Q K^T (16 q-rows x 64 keys per wave) ----
      f32x4 sa[4];
#pragma unroll
      for (int kt = 0; kt < 4; kt++)
#pragma unroll
        for (int jj = 0; jj < 4; jj++) sa[kt][jj] = 0.0f;
      const u16* kl = Klds + cur * 8192;
      __builtin_amdgcn_s_setprio(1);
#pragma unroll
      for (int kk = 0; kk < 4; kk++) {
#pragma unroll
        for (int kt = 0; kt < 4; kt++) {
          const int row = kt*16 + lr;
          const bf16x8 kf = *reinterpret_cast<const bf16x8*>(
              kl + row * 128 + ((kk*32 + lg*8) ^ ((row & 7) * 8)));
          sa[kt] = mfma_bf16(qf[kk], kf, sa[kt]);
        }
      }
      __builtin_amdgcn_s_setprio(0);

      // causal mask: only the diagonal tile (kv == j) straddles
      if (kv == j) {
#pragma unroll
        for (int kt = 0; kt < 4; kt++) {
          const int key = kt*16 + lr;                  // within tile
#pragma unroll
          for (int r = 0; r < 4; r++) {
            const int qv = w*16 + lg*4 + r;            // within tile
            if (key > qv) sa[kt][r] = -1e9f;
          }
        }
      }

      // defer-max (THR=8): lane-local check, rescale rarely
      float pm[4];
#pragma unroll
      for (int r = 0; r < 4; r++)
        pm[r] = fmaxf(fmaxf(sa[0][r], sa[1][r]), fmaxf(sa[2][r], sa[3][r]));
      bool ok = true;
#pragma unroll
      for (int r = 0; r < 4; r++) ok = ok && (pm[r] <= m[r] + 8.0f);
      if (!__all(ok)) {
#pragma unroll
        for (int r = 0; r < 4; r++) {
          float t = pm[r];
#pragma unroll
          for (int d = 1; d < 16; d <<= 1) t = fmaxf(t, __shfl_xor(t, d));
          const float mnew = fmaxf(m[r], t);
          const float corr = exp2f(m[r] - mnew);
          lsum[r] *= corr;
#pragma unroll
          for (int dt = 0; dt < 8; dt++) oacc[dt][r] *= corr;
          m[r] = mnew;
        }
      }

      // exp2 + lane-partial sums + P -> per-wave LDS
#pragma unroll
      for (int r = 0; r < 4; r++) {
        float rs = 0.0f;
#pragma unroll
        for (int kt = 0; kt < 4; kt++) {
          const float e = exp2f(sa[kt][r] - m[r]);
          rs += e;
          PL[w][lg*4 + r][kt*16 + lr] = f2bq(e);
        }
        lsum[r] += rs;
      }

      // ---- O += P V ----
      __builtin_amdgcn_s_setprio(1);
#pragma unroll
      for (int kk2 = 0; kk2 < 2; kk2++) {
        const bf16x8 pa = *reinterpret_cast<const bf16x8*>(&PL[w][lr][kk2*32 + lg*8]);
#pragma unroll
        for (int dt = 0; dt < 8; dt++) {
          const int row = dt*16 + lr;
          const bf16x8 vb = *reinterpret_cast<const bf16x8*>(
              VT + row * 64 + ((kk2*32 + lg*8) ^ (((row ^ (row >> 3)) & 7) * 8)));
          oacc[dt] = mfma_bf16(pa, vb, oacc[dt]);
        }
      }
      __builtin_amdgcn_s_setprio(0);

      if (hasnext) cur ^= 1;
    }

    // epilogue: reduce lane-partial lsum across 16 lanes, normalize, store
    float inv[4];
#pragma unroll
    for (int r = 0; r < 4; r++) {
      float t = lsum[r];
#pragma unroll
      for (int d = 1; d < 16; d <<= 1) t += __shfl_xor(t, d);
      inv[r] = 1.0f / t;
    }
#pragma unroll
    for (int dt = 0; dt < 8; dt++)
#pragma unroll
      for (int r = 0; r < 4; r++) {
        const size_t row = (size_t)(b*SS + q0 + w*16 + lg*4 + r);
        Op[row * DD + h*DKK + dt*16 + lr] = f2bq(oacc[dt][r] * inv[r]);
      }
  }
}

extern "C" void kernel_launch(void* const* d_in, const int* in_sizes, int n_in,
                              void* d_out, int out_size, void* d_ws, size_t ws_size,
                              hipStream_t stream) {
  const float* q  = (const float*)d_in[0];
  const float* k  = (const float*)d_in[1];
  const float* v  = (const float*)d_in[2];
  const float* fa = (const float*)d_in[4];
  const float* wq = (const float*)d_in[5];
  const float* bq = (const float*)d_in[6];
  const float* wk = (const float*)d_in[7];
  const float* bk = (const float*)d_in[8];
  const float* wv = (const float*)d_in[9];
  const float* bv = (const float*)d_in[10];
  const float* wo = (const float*)d_in[11];
  const float* bo = (const float*)d_in[12];

  float* cs = (float*)d_ws;
  u16* bf = (u16*)((char*)d_ws + (size_t)262144 * sizeof(float));
  const size_t NX = (size_t)MM * DD;
  const size_t NW = (size_t)DD * DD;
  u16* q_bf  = bf;
  u16* k_bf  = q_bf + NX;
  u16* v_bf  = k_bf + NX;
  u16* wq_bf = v_bf + NX;
  u16* wk_bf = wq_bf + NW;
  u16* wv_bf = wk_bf + NW;
  u16* wo_bf = wv_bf + NW;
  u16* Qp    = wo_bf + NW;
  u16* Kp    = Qp + NX;
  u16* Vp    = Kp + NX;
  u16* Ao    = Vp + NX;

  F2BArgs fa7;
  fa7.src[0] = q;  fa7.dst[0] = q_bf;
  fa7.src[1] = k;  fa7.dst[1] = k_bf;
  fa7.src[2] = v;  fa7.dst[2] = v_bf;
  fa7.src[3] = wq; fa7.dst[3] = wq_bf;
  fa7.src[4] = wk; fa7.dst[4] = wk_bf;
  fa7.src[5] = wv; fa7.dst[5] = wv_bf;
  fa7.src[6] = wo; fa7.dst[6] = wo_bf;
  fa7.fa = fa;     fa7.cs = cs;
  // 20480 conversion blocks + 64 cos/sin-table blocks
  k_f2bf_all<<<dim3(20544), 256, 0, stream>>>(fa7);

  // fused QKV projections: dbuf 128^2 kernel + XCD swizzle, 32x16x3 blocks
  GemmArgs gq;
  gq.job[0] = GemmJob{ q_bf, wq_bf, bq, (void*)Qp, 3 };
  gq.job[1] = GemmJob{ k_bf, wk_bf, bk, (void*)Kp, 1 };
  gq.job[2] = GemmJob{ v_bf, wv_bf, bv, (void*)Vp, 0 };
  k_gemm3<<<dim3(MM/128, DD/128, 3), 256, 0, stream>>>(gq, cs);

  // attention: 512 paired blocks (cost-33 uniform), all resident, no tail
  k_attn<<<dim3(512), 256, 0, stream>>>(Qp, Kp, Vp, Ao);

  // output projection: 512 blocks = exactly 2 blocks/CU, one round
  GemmArgs go;
  go.job[0] = GemmJob{ Ao, wo_bf, bo, d_out, 2 };
  go.job[1] = go.job[0];
  go.job[2] = go.job[0];
  k_gemm3<<<dim3(MM/128, DD/128, 1), 256, 0, stream>>>(go, cs);
}